// Round 2
// baseline (146.764 us; speedup 1.0000x reference)
//
#include <hip/hip_runtime.h>
#include <cstdint>
#include <cmath>

using short8  = __attribute__((ext_vector_type(8))) short;
using short4v = __attribute__((ext_vector_type(4))) short;
using floatx4 = __attribute__((ext_vector_type(4))) float;

__device__ __forceinline__ short f2bf(float f) {
  union { float f; unsigned u; } x; x.f = f;
  unsigned r = x.u + 0x7FFFu + ((x.u >> 16) & 1u);
  return (short)(r >> 16);
}

__device__ __forceinline__ void gl_lds16(const short* g, short* l) {
  __builtin_amdgcn_global_load_lds(
      (const __attribute__((address_space(1))) void*)g,
      (__attribute__((address_space(3))) void*)l, 16, 0, 0);
}

// ===========================================================================
// prep: cast/transpose keys+queries, pack 5 weights to bf16.
// r6: w1 repacked to [c0(8)][dk(3)][co(512)][ci32] so conv_k3's per-c0
// weight chunk is a linear 12 KB run (perfect coalescing + linear LDS dest
// for global_load_lds). Other weights unchanged.
// ===========================================================================
__global__ __launch_bounds__(256) void prep_kernel(
    const float* __restrict__ keys, const float* __restrict__ queries,
    const float* __restrict__ kw1, const float* __restrict__ kw2,
    const float* __restrict__ qw1, const float* __restrict__ qw2,
    const float* __restrict__ qw3,
    short* __restrict__ kT0, short* __restrict__ qT0,
    short* __restrict__ w1, short* __restrict__ w2, short* __restrict__ w3,
    short* __restrict__ w4, short* __restrict__ w5)
{
  const int bid = blockIdx.x, tid = threadIdx.x;
  __shared__ float xs[32][65];

  if (bid < 1136) {
    const float* src; short* dst; int CIN, T, CP, bx, by, b;
    if (bid < 512) {
      src = keys; dst = kT0; CIN = 256; T = 200; CP = 256;
      bx = bid & 3; by = (bid >> 2) & 7; b = bid >> 5;
    } else {
      int b2 = bid - 512;
      src = queries; dst = qT0; CIN = 80; T = 800; CP = 96;
      bx = b2 % 13; by = (b2 / 13) % 3; b = b2 / 39;
    }
    const int t0 = bx * 64, ci0 = by * 32;
    for (int i = tid; i < 32 * 64; i += 256) {
      int row = i >> 6, col = i & 63;
      float v = 0.f;
      if (ci0 + row < CIN && t0 + col < T)
        v = src[((size_t)b * CIN + ci0 + row) * T + t0 + col];
      xs[row][col] = v;
    }
    __syncthreads();
    int t = tid >> 2, c8 = (tid & 3) * 8;
    if (t0 + t < T) {
      short8 o;
      #pragma unroll
      for (int j = 0; j < 8; ++j) o[j] = f2bf(xs[c8 + j][t]);
      *(short8*)&dst[((size_t)b * T + t0 + t) * CP + ci0 + c8] = o;
    }
  } else {
    int blk = bid - 1136;
    const float* src; short* dst; int base;
    int CoP, CiP, Cout, CIN, K; bool isW1 = false;
    if      (blk < 384) { src=kw1; dst=w1; base=0;   CoP=512; CiP=256; Cout=512; CIN=256; K=3; isW1=true; }
    else if (blk < 432) { src=kw2; dst=w2; base=384; CoP=96;  CiP=512; Cout=80;  CIN=512; K=1; }
    else if (blk < 486) { src=qw1; dst=w3; base=432; CoP=192; CiP=96;  Cout=160; CIN=80;  K=3; }
    else if (blk < 504) { src=qw2; dst=w4; base=486; CoP=96;  CiP=192; Cout=80;  CIN=160; K=1; }
    else                { src=qw3; dst=w5; base=504; CoP=96;  CiP=96;  Cout=80;  CIN=80;  K=1; }
    int tot = K * CoP * CiP;
    int b0 = (blk - base) * 1024;
    for (int e = 0; e < 4; ++e) {
      int gi = b0 + e * 256 + tid;
      if (gi < tot) {
        int dk  = gi / (CoP * CiP);
        int rem = gi - dk * (CoP * CiP);
        int co  = rem / CiP, ci = rem - (rem / CiP) * CiP;
        float v = (co < Cout && ci < CIN) ? src[((size_t)co * CIN + ci) * K + dk] : 0.f;
        int idx = gi;
        if (isW1) idx = (((ci >> 5) * 3 + dk) * 512 + co) * 32 + (ci & 31);
        dst[idx] = f2bf(v);
      }
    }
  }
}

// ===========================================================================
// conv_k3 (r6): blocks [0,512) = key conv1 (256->512 k3 +ReLU) -> kT1.
//   x-tile (66 x 256ch, 34.8 KB) staged ONCE; weights double-buffered via
//   global_load_lds width-16 (linear 12 KB chunks from repacked w1);
//   ONE barrier per c0 (was 2 + full restage).
// blocks [512,720) = query chain per 64-t tile -> qF; x staged once.
// ===========================================================================
__global__ __launch_bounds__(256) void conv_k3_kernel(
    const short* __restrict__ kT0, const short* __restrict__ qT0,
    const short* __restrict__ w1, const short* __restrict__ w3,
    const short* __restrict__ w4, const short* __restrict__ w5,
    const float* __restrict__ kb1, const float* __restrict__ qb1,
    const float* __restrict__ qb2, const float* __restrict__ qb3,
    short* __restrict__ kT1, short* __restrict__ qF)
{
  __shared__ __align__(16) short smem[29904];   // 59,808 B
  const int tid = threadIdx.x, wid = tid >> 6, lane = tid & 63;
  const int q = lane >> 4, m = lane & 15;

  if (blockIdx.x < 512) {
    // ---- KEY CONV1: x once, weights dbuf ----
    const int blk = blockIdx.x;
    const int b = blk >> 5, co0 = ((blk >> 2) & 7) * 64, t0 = (blk & 3) * 64;
    const int wy = wid >> 1, wx = wid & 1;
    short* xs = smem;                          // [66][264]
    short* asb0 = smem + 17424;                // [3][64][32] = 6144 shorts
    short* asb1 = smem + 23568;

    floatx4 acc[2][2];
    #pragma unroll
    for (int i = 0; i < 2; ++i)
      #pragma unroll
      for (int j = 0; j < 2; ++j) acc[i][j] = (floatx4){0.f, 0.f, 0.f, 0.f};

    // stage full x tile once: 66 rows x 32 int4
    for (int i = tid; i < 66 * 32; i += 256) {
      int row = i >> 5, c8 = (i & 31) * 8;
      int t = t0 + row - 1;
      int4 v = {0, 0, 0, 0};
      if (t >= 0 && t < 200)
        v = *(const int4*)&kT0[((size_t)b * 200 + t) * 256 + c8];
      *(int4*)&xs[row * 264 + c8] = v;
    }
    // issue weight chunk c0=0 into asb0 (3 x 4KB linear runs)
    {
      const int wv = tid >> 6;
      #pragma unroll
      for (int c = 0; c < 3; ++c) {
        const short* g = w1 + ((size_t)(0 * 3 + c) * 512 + co0) * 32 + tid * 8;
        short* l = asb0 + c * 2048 + wv * 512;
        gl_lds16(g, l);
      }
    }
    __syncthreads();   // drains x stores + weight loads

    int cur = 0;
    for (int c0 = 0; c0 < 8; ++c0) {
      short* as_cur = cur ? asb1 : asb0;
      if (c0 < 7) {
        short* asn = cur ? asb0 : asb1;
        const int wv = tid >> 6;
        #pragma unroll
        for (int c = 0; c < 3; ++c) {
          const short* g = w1 + ((size_t)((c0 + 1) * 3 + c) * 512 + co0) * 32 + tid * 8;
          gl_lds16(g, asn + c * 2048 + wv * 512);
        }
      }
      #pragma unroll
      for (int dk = 0; dk < 3; ++dk) {
        short8 fa0 = *(const short8*)&as_cur[dk * 2048 + (wy * 32 + m) * 32 + q * 8];
        short8 fa1 = *(const short8*)&as_cur[dk * 2048 + (wy * 32 + 16 + m) * 32 + q * 8];
        #pragma unroll
        for (int j = 0; j < 2; ++j) {
          short8 fb = *(const short8*)&xs[(wx * 32 + j * 16 + m + dk) * 264 + c0 * 32 + q * 8];
          acc[0][j] = __builtin_amdgcn_mfma_f32_16x16x32_bf16(fa0, fb, acc[0][j], 0, 0, 0);
          acc[1][j] = __builtin_amdgcn_mfma_f32_16x16x32_bf16(fa1, fb, acc[1][j], 0, 0, 0);
        }
      }
      __syncthreads();   // drains next-chunk loads; guards buffer swap
      cur ^= 1;
    }
    #pragma unroll
    for (int i = 0; i < 2; ++i) {
      #pragma unroll
      for (int j = 0; j < 2; ++j) {
        #pragma unroll
        for (int r = 0; r < 4; ++r) {
          int co = co0 + wy * 32 + i * 16 + q * 4 + r;
          int t  = t0 + wx * 32 + j * 16 + m;
          if (t < 200) {
            float v = fmaxf(acc[i][j][r] + kb1[co], 0.f);
            kT1[((size_t)b * 200 + t) * 512 + co] = f2bf(v);
          }
        }
      }
    }
  } else {
    // ---- QUERY CHAIN (r6: x staged once, no per-c0 barriers) ----
    const int qbid = blockIdx.x - 512;
    const int b = qbid / 13, t0 = (qbid % 13) * 64;
    short* xs2 = smem;            // [66][104]
    short* y1c = smem + 6864;     // [6][64][40]
    short* y2c = smem + 22224;    // [3][64][40]

    floatx4 accq[3][4];
    #pragma unroll
    for (int f = 0; f < 3; ++f)
      #pragma unroll
      for (int tf = 0; tf < 4; ++tf) accq[f][tf] = (floatx4){0.f, 0.f, 0.f, 0.f};

    // stage full x tile once: 66 rows x 12 int4 (96 channels)
    for (int i = tid; i < 66 * 12; i += 256) {
      int row = i / 12, g = i - (i / 12) * 12;
      int t = t0 + row - 1;
      int4 v = {0, 0, 0, 0};
      if (t >= 0 && t < 800)
        v = *(const int4*)&qT0[((size_t)b * 800 + t) * 96 + g * 8];
      *(int4*)&xs2[row * 104 + g * 8] = v;
    }
    __syncthreads();

    for (int c0 = 0; c0 < 3; ++c0) {
      #pragma unroll
      for (int dk = 0; dk < 3; ++dk) {
        short8 fa[3];
        #pragma unroll
        for (int f = 0; f < 3; ++f)
          fa[f] = *(const short8*)&w3[((size_t)(dk * 192 + wid * 48 + f * 16 + m)) * 96
                                      + c0 * 32 + q * 8];
        #pragma unroll
        for (int tf = 0; tf < 4; ++tf) {
          short8 fb = *(const short8*)&xs2[(tf * 16 + m + dk) * 104 + c0 * 32 + q * 8];
          #pragma unroll
          for (int f = 0; f < 3; ++f)
            accq[f][tf] = __builtin_amdgcn_mfma_f32_16x16x32_bf16(fa[f], fb, accq[f][tf], 0, 0, 0);
        }
      }
    }
    __syncthreads();
    #pragma unroll
    for (int f = 0; f < 3; ++f) {
      #pragma unroll
      for (int tf = 0; tf < 4; ++tf) {
        int co = wid * 48 + f * 16 + q * 4;
        int t  = tf * 16 + m;
        short4v o;
        #pragma unroll
        for (int r = 0; r < 4; ++r) {
          float bv = (co + r < 160) ? qb1[co + r] : 0.f;
          o[r] = f2bf(fmaxf(accq[f][tf][r] + bv, 0.f));
        }
        *(short4v*)&y1c[(co >> 5) * 2560 + t * 40 + (co & 31)] = o;
      }
    }
    __syncthreads();

    floatx4 acc2q[6];
    #pragma unroll
    for (int f = 0; f < 6; ++f) acc2q[f] = (floatx4){0.f, 0.f, 0.f, 0.f};
    #pragma unroll
    for (int c = 0; c < 6; ++c) {
      short8 fb = *(const short8*)&y1c[c * 2560 + (wid * 16 + m) * 40 + q * 8];
      #pragma unroll
      for (int f = 0; f < 6; ++f) {
        short8 fa = *(const short8*)&w4[((size_t)(f * 16 + m)) * 192 + c * 32 + q * 8];
        acc2q[f] = __builtin_amdgcn_mfma_f32_16x16x32_bf16(fa, fb, acc2q[f], 0, 0, 0);
      }
    }
    #pragma unroll
    for (int f = 0; f < 6; ++f) {
      int co = f * 16 + q * 4;
      int t  = wid * 16 + m;
      short4v o;
      #pragma unroll
      for (int r = 0; r < 4; ++r) {
        float bv = (co + r < 80) ? qb2[co + r] : 0.f;
        o[r] = f2bf(fmaxf(acc2q[f][r] + bv, 0.f));
      }
      *(short4v*)&y2c[(co >> 5) * 2560 + t * 40 + (co & 31)] = o;
    }
    __syncthreads();

    floatx4 acc3q[6];
    #pragma unroll
    for (int f = 0; f < 6; ++f) acc3q[f] = (floatx4){0.f, 0.f, 0.f, 0.f};
    #pragma unroll
    for (int c = 0; c < 3; ++c) {
      short8 fb = *(const short8*)&y2c[c * 2560 + (wid * 16 + m) * 40 + q * 8];
      #pragma unroll
      for (int f = 0; f < 6; ++f) {
        short8 fa = *(const short8*)&w5[((size_t)(f * 16 + m)) * 96 + c * 32 + q * 8];
        acc3q[f] = __builtin_amdgcn_mfma_f32_16x16x32_bf16(fa, fb, acc3q[f], 0, 0, 0);
      }
    }
    int t = t0 + wid * 16 + m;
    if (t < 800) {
      #pragma unroll
      for (int f = 0; f < 6; ++f) {
        int co = f * 16 + q * 4;
        short4v o;
        #pragma unroll
        for (int r = 0; r < 4; ++r) {
          float bv = (co + r < 80) ? qb3[co + r] : 0.f;
          o[r] = f2bf(acc3q[f][r] + bv);
        }
        *(short4v*)&qF[((size_t)b * 800 + t) * 96 + co] = o;
      }
    }
  }
}

// ===========================================================================
// kconv2 (r5-verified): key 512->80 k1, 208 one-wave blocks.
// ===========================================================================
__global__ __launch_bounds__(64) void kconv2_kernel(
    const short* __restrict__ kT1, const short* __restrict__ w2,
    const float* __restrict__ kb2, short* __restrict__ kF)
{
  const int blk = blockIdx.x;
  const int b = blk / 13, t0 = (blk - b * 13) * 16;
  const int lane = threadIdx.x & 63;
  const int q = lane >> 4, m = lane & 15;
  const int t = t0 + m;
  const bool tv = (t < 200);

  floatx4 acc[6];
  #pragma unroll
  for (int f = 0; f < 6; ++f) acc[f] = (floatx4){0.f, 0.f, 0.f, 0.f};

  #pragma unroll
  for (int c = 0; c < 16; ++c) {
    short8 fb;
    if (tv) fb = *(const short8*)&kT1[((size_t)b * 200 + t) * 512 + c * 32 + q * 8];
    else    fb = (short8){0,0,0,0,0,0,0,0};
    #pragma unroll
    for (int f = 0; f < 6; ++f) {
      short8 fa = *(const short8*)&w2[((size_t)(f * 16 + m)) * 512 + c * 32 + q * 8];
      acc[f] = __builtin_amdgcn_mfma_f32_16x16x32_bf16(fa, fb, acc[f], 0, 0, 0);
    }
  }
  if (tv) {
    #pragma unroll
    for (int f = 0; f < 6; ++f) {
      int co = f * 16 + q * 4;
      short4v o;
      #pragma unroll
      for (int r = 0; r < 4; ++r) {
        float bv = (co + r < 80) ? kb2[co + r] : 0.f;
        o[r] = f2bf(acc[f][r] + bv);
      }
      *(short4v*)&kF[((size_t)b * 200 + t) * 96 + co] = o;
    }
  }
}

// ===========================================================================
// Attention (r5-verified): S = q.k^T, q2 cancels, in-register log_softmax,
// LDS-staged coalesced float4 epilogue.
// ===========================================================================
__global__ __launch_bounds__(256) void attn_mfma(
    const short* __restrict__ qT, const short* __restrict__ kT,
    const float* __restrict__ prior, float* __restrict__ out)
{
  const int b = blockIdx.y, t1_0 = blockIdx.x * 64;
  const int tid = threadIdx.x, wid = tid >> 6, lane = tid & 63;
  const int q = lane >> 4, m = lane & 15;

  __shared__ __align__(16) char smem[51200];
  short* aq = (short*)smem;
  short* bk = (short*)(smem + 13312);
  float* k2s = (float*)(smem + 29952);
  float* sstage = (float*)smem;

  floatx4 acc[13];
  #pragma unroll
  for (int f = 0; f < 13; ++f) acc[f] = (floatx4){0.f, 0.f, 0.f, 0.f};

  for (int i = tid; i < 64 * 12; i += 256) {
    int row = i / 12, g = i - (i / 12) * 12;
    int4 v = {0, 0, 0, 0};
    if (t1_0 + row < 800)
      v = *(const int4*)&qT[((size_t)b * 800 + t1_0 + row) * 96 + g * 8];
    *(int4*)&aq[row * 104 + g * 8] = v;
  }

  float k2acc = 0.f;
  for (int c = 0; c < 3; ++c) {
    __syncthreads();
    for (int i = tid; i < 208 * 4; i += 256) {
      int row = i >> 2, g = i & 3;
      int4 v = {0, 0, 0, 0};
      if (row < 200)
        v = *(const int4*)&kT[((size_t)b * 200 + row) * 96 + c * 32 + g * 8];
      *(int4*)&bk[row * 40 + g * 8] = v;
    }
    __syncthreads();
    if (tid < 208) {
      #pragma unroll
      for (int g = 0; g < 4; ++g) {
        short8 s = *(const short8*)&bk[tid * 40 + g * 8];
        #pragma unroll
        for (int j = 0; j < 8; ++j) {
          union { unsigned u; float f; } x; x.u = ((unsigned)(unsigned short)s[j]) << 16;
          k2acc = fmaf(x.f, x.f, k2acc);
        }
      }
    }
    short8 fa = *(const short8*)&aq[(wid * 16 + m) * 104 + c * 32 + q * 8];
    #pragma unroll
    for (int f = 0; f < 13; ++f) {
      short8 fb = *(const short8*)&bk[(f * 16 + m) * 40 + q * 8];
      acc[f] = __builtin_amdgcn_mfma_f32_16x16x32_bf16(fa, fb, acc[f], 0, 0, 0);
    }
  }
  if (tid < 208) k2s[tid] = k2acc;
  __syncthreads();

  float k2v[13];
  #pragma unroll
  for (int f = 0; f < 13; ++f) k2v[f] = k2s[f * 16 + m];

  float mx[4] = {-INFINITY, -INFINITY, -INFINITY, -INFINITY};
  #pragma unroll
  for (int f = 0; f < 13; ++f) {
    bool valid = (f * 16 + m) < 200;
    #pragma unroll
    for (int r = 0; r < 4; ++r) {
      float v = valid ? (0.001f * acc[f][r] - 0.0005f * k2v[f]) : -INFINITY;
      acc[f][r] = v;
      mx[r] = fmaxf(mx[r], v);
    }
  }
  #pragma unroll
  for (int msk = 1; msk < 16; msk <<= 1)
    #pragma unroll
    for (int r = 0; r < 4; ++r) mx[r] = fmaxf(mx[r], __shfl_xor(mx[r], msk));
  float sm[4] = {0.f, 0.f, 0.f, 0.f};
  #pragma unroll
  for (int f = 0; f < 13; ++f)
    #pragma unroll
    for (int r = 0; r < 4; ++r) sm[r] += __expf(acc[f][r] - mx[r]);
  #pragma unroll
  for (int msk = 1; msk < 16; msk <<= 1)
    #pragma unroll
    for (int r = 0; r < 4; ++r) sm[r] += __shfl_xor(sm[r], msk);
  float lse[4];
  #pragma unroll
  for (int r = 0; r < 4; ++r) lse[r] = mx[r] + __logf(sm[r]);

  __syncthreads();
  #pragma unroll
  for (int f = 0; f < 13; ++f) {
    int col = f * 16 + m;
    if (col < 200) {
      #pragma unroll
      for (int r = 0; r < 4; ++r)
        sstage[(wid * 16 + q * 4 + r) * 200 + col] = acc[f][r] - lse[r];
    }
  }
  __syncthreads();

  for (int i = tid; i < 64 * 50; i += 256) {
    int row = i / 50, seg = i - (i / 50) * 50;
    int t1 = t1_0 + row;
    if (t1 < 800) {
      size_t o = ((size_t)b * 800 + t1) * 200 + seg * 4;
      floatx4 pv = *(const floatx4*)&prior[o];
      floatx4 sv = *(const floatx4*)&sstage[row * 200 + seg * 4];
      floatx4 ov;
      #pragma unroll
      for (int j = 0; j < 4; ++j) ov[j] = sv[j] + __logf(pv[j] + 1e-8f);
      *(floatx4*)&out[o] = ov;
    }
  }
}

extern "C" void kernel_launch(void* const* d_in, const int* in_sizes, int n_in,
                              void* d_out, int out_size, void* d_ws, size_t ws_size,
                              hipStream_t stream) {
  const float* queries = (const float*)d_in[0];
  const float* keys    = (const float*)d_in[1];
  const float* prior   = (const float*)d_in[2];
  const float* kw1 = (const float*)d_in[3];
  const float* kb1 = (const float*)d_in[4];
  const float* kw2 = (const float*)d_in[5];
  const float* kb2 = (const float*)d_in[6];
  const float* qw1 = (const float*)d_in[7];
  const float* qb1 = (const float*)d_in[8];
  const float* qw2 = (const float*)d_in[9];
  const float* qb2 = (const float*)d_in[10];
  const float* qw3 = (const float*)d_in[11];
  const float* qb3 = (const float*)d_in[12];
  float* out = (float*)d_out;

  short* p = (short*)d_ws;
  short* kT0 = p;  p += (size_t)3200 * 256;
  short* qT0 = p;  p += (size_t)12800 * 96;
  short* w1  = p;  p += (size_t)3 * 512 * 256;
  short* w2  = p;  p += (size_t)96 * 512;
  short* w3  = p;  p += (size_t)3 * 192 * 96;
  short* w4  = p;  p += (size_t)96 * 192;
  short* w5  = p;  p += (size_t)96 * 96;
  short* kT1 = p;  p += (size_t)3200 * 512;
  short* kF  = p;  p += (size_t)3200 * 96;
  short* qF  = p;  p += (size_t)12800 * 96;

  prep_kernel<<<dim3(1649), 256, 0, stream>>>(keys, queries, kw1, kw2, qw1, qw2, qw3,
                                              kT0, qT0, w1, w2, w3, w4, w5);
  conv_k3_kernel<<<dim3(720), 256, 0, stream>>>(kT0, qT0, w1, w3, w4, w5,
                                                kb1, qb1, qb2, qb3, kT1, qF);
  kconv2_kernel<<<dim3(208), 64, 0, stream>>>(kT1, w2, kb2, kF);
  attn_mfma<<<dim3(13, 16), 256, 0, stream>>>(qF, kF, prior, out);
}

// Round 4
// 140.048 us; speedup vs baseline: 1.0480x; 1.0480x over previous
//
#include <hip/hip_runtime.h>
#include <cstdint>
#include <cmath>

using short8  = __attribute__((ext_vector_type(8))) short;
using short4v = __attribute__((ext_vector_type(4))) short;
using floatx4 = __attribute__((ext_vector_type(4))) float;

__device__ __forceinline__ short f2bf(float f) {
  union { float f; unsigned u; } x; x.f = f;
  unsigned r = x.u + 0x7FFFu + ((x.u >> 16) & 1u);
  return (short)(r >> 16);
}

__device__ __forceinline__ void gl_lds16(const short* g, short* l) {
  __builtin_amdgcn_global_load_lds(
      (const __attribute__((address_space(1))) void*)g,
      (__attribute__((address_space(3))) void*)l, 16, 0, 0);
}

// ===========================================================================
// prep (r6-verified): cast/transpose keys+queries, pack 5 weights to bf16.
// w1 repacked to [c0(8)][dk(3)][co(512)][ci32] -> linear 4KB gl_lds chunks.
// ===========================================================================
__global__ __launch_bounds__(256) void prep_kernel(
    const float* __restrict__ keys, const float* __restrict__ queries,
    const float* __restrict__ kw1, const float* __restrict__ kw2,
    const float* __restrict__ qw1, const float* __restrict__ qw2,
    const float* __restrict__ qw3,
    short* __restrict__ kT0, short* __restrict__ qT0,
    short* __restrict__ w1, short* __restrict__ w2, short* __restrict__ w3,
    short* __restrict__ w4, short* __restrict__ w5)
{
  const int bid = blockIdx.x, tid = threadIdx.x;
  __shared__ float xs[32][65];

  if (bid < 1136) {
    const float* src; short* dst; int CIN, T, CP, bx, by, b;
    if (bid < 512) {
      src = keys; dst = kT0; CIN = 256; T = 200; CP = 256;
      bx = bid & 3; by = (bid >> 2) & 7; b = bid >> 5;
    } else {
      int b2 = bid - 512;
      src = queries; dst = qT0; CIN = 80; T = 800; CP = 96;
      bx = b2 % 13; by = (b2 / 13) % 3; b = b2 / 39;
    }
    const int t0 = bx * 64, ci0 = by * 32;
    for (int i = tid; i < 32 * 64; i += 256) {
      int row = i >> 6, col = i & 63;
      float v = 0.f;
      if (ci0 + row < CIN && t0 + col < T)
        v = src[((size_t)b * CIN + ci0 + row) * T + t0 + col];
      xs[row][col] = v;
    }
    __syncthreads();
    int t = tid >> 2, c8 = (tid & 3) * 8;
    if (t0 + t < T) {
      short8 o;
      #pragma unroll
      for (int j = 0; j < 8; ++j) o[j] = f2bf(xs[c8 + j][t]);
      *(short8*)&dst[((size_t)b * T + t0 + t) * CP + ci0 + c8] = o;
    }
  } else {
    int blk = bid - 1136;
    const float* src; short* dst; int base;
    int CoP, CiP, Cout, CIN, K; bool isW1 = false;
    if      (blk < 384) { src=kw1; dst=w1; base=0;   CoP=512; CiP=256; Cout=512; CIN=256; K=3; isW1=true; }
    else if (blk < 432) { src=kw2; dst=w2; base=384; CoP=96;  CiP=512; Cout=80;  CIN=512; K=1; }
    else if (blk < 486) { src=qw1; dst=w3; base=432; CoP=192; CiP=96;  Cout=160; CIN=80;  K=3; }
    else if (blk < 504) { src=qw2; dst=w4; base=486; CoP=96;  CiP=192; Cout=80;  CIN=160; K=1; }
    else                { src=qw3; dst=w5; base=504; CoP=96;  CiP=96;  Cout=80;  CIN=80;  K=1; }
    int tot = K * CoP * CiP;
    int b0 = (blk - base) * 1024;
    for (int e = 0; e < 4; ++e) {
      int gi = b0 + e * 256 + tid;
      if (gi < tot) {
        int dk  = gi / (CoP * CiP);
        int rem = gi - dk * (CoP * CiP);
        int co  = rem / CiP, ci = rem - (rem / CiP) * CiP;
        float v = (co < Cout && ci < CIN) ? src[((size_t)co * CIN + ci) * K + dk] : 0.f;
        int idx = gi;
        if (isW1) idx = (((ci >> 5) * 3 + dk) * 512 + co) * 32 + (ci & 31);
        dst[idx] = f2bf(v);
      }
    }
  }
}

// ===========================================================================
// conv_k3 (r8 = r7 compile-fixed): LDS 46,080 B -> 3 blocks/CU, full
// 720-block residency. Key branch: x-slice dbuf (2x5280B) + weight dbuf via
// gl_lds (2x12288B), ONE barrier per c0. Query branch: y2c aliases dead xs2.
// NOTE: no pointer arrays into LDS (gfx950 addrspacecast initializer bug) —
// buffers selected via ternary offsets.
// ===========================================================================
__global__ __launch_bounds__(256) void conv_k3_kernel(
    const short* __restrict__ kT0, const short* __restrict__ qT0,
    const short* __restrict__ w1, const short* __restrict__ w3,
    const short* __restrict__ w4, const short* __restrict__ w5,
    const float* __restrict__ kb1, const float* __restrict__ qb1,
    const float* __restrict__ qb2, const float* __restrict__ qb3,
    short* __restrict__ kT1, short* __restrict__ qF)
{
  __shared__ __align__(16) short smem[23040];   // 46,080 B
  const int tid = threadIdx.x, wid = tid >> 6, lane = tid & 63;
  const int q = lane >> 4, m = lane & 15;

  if (blockIdx.x < 512) {
    // ---- KEY CONV1: x-slice dbuf + weight dbuf, 1 barrier/c0 ----
    const int blk = blockIdx.x;
    const int bb = blk >> 5, co0 = ((blk >> 2) & 7) * 64, t0 = (blk & 3) * 64;
    const int wy = wid >> 1, wx = wid & 1;
    const int wv = tid >> 6;

    floatx4 acc[2][2];
    #pragma unroll
    for (int i = 0; i < 2; ++i)
      #pragma unroll
      for (int j = 0; j < 2; ++j) acc[i][j] = (floatx4){0.f, 0.f, 0.f, 0.f};

    auto xload = [&](int c0s, int4& a, int4& bvv) {
      { int row = tid >> 2, g = tid & 3;
        int t = t0 + row - 1;
        a = (int4){0,0,0,0};
        if (t >= 0 && t < 200)
          a = *(const int4*)&kT0[((size_t)bb * 200 + t) * 256 + c0s * 32 + g * 8]; }
      bvv = (int4){0,0,0,0};
      if (tid < 8) {
        int i1 = tid + 256, row = i1 >> 2, g = i1 & 3;
        int t = t0 + row - 1;
        if (t >= 0 && t < 200)
          bvv = *(const int4*)&kT0[((size_t)bb * 200 + t) * 256 + c0s * 32 + g * 8];
      }
    };
    auto xstore = [&](const int4& a, const int4& bvv, int xoff) {
      { int row = tid >> 2, g = tid & 3; *(int4*)&smem[xoff + row * 40 + g * 8] = a; }
      if (tid < 8) { int i1 = tid + 256, row = i1 >> 2, g = i1 & 3;
        *(int4*)&smem[xoff + row * 40 + g * 8] = bvv; }
    };
    auto wissue = [&](int c0s, int aoff) {
      #pragma unroll
      for (int c = 0; c < 3; ++c) {
        const short* g = w1 + ((size_t)(c0s * 3 + c) * 512 + co0) * 32 + tid * 8;
        gl_lds16(g, &smem[aoff + c * 2048 + wv * 512]);
      }
    };

    { int4 a, bvv; xload(0, a, bvv); wissue(0, 5280); xstore(a, bvv, 0); }
    __syncthreads();

    int cur = 0;
    for (int c0 = 0; c0 < 8; ++c0) {
      const int xo = cur ? 2640 : 0;
      const int ao = cur ? 11424 : 5280;
      int4 xa, xb;
      if (c0 < 7) {
        wissue(c0 + 1, cur ? 5280 : 11424);
        xload(c0 + 1, xa, xb);
      }
      #pragma unroll
      for (int dk = 0; dk < 3; ++dk) {
        short8 fa0 = *(const short8*)&smem[ao + dk * 2048 + (wy * 32 + m) * 32 + q * 8];
        short8 fa1 = *(const short8*)&smem[ao + dk * 2048 + (wy * 32 + 16 + m) * 32 + q * 8];
        #pragma unroll
        for (int j = 0; j < 2; ++j) {
          short8 fb = *(const short8*)&smem[xo + (wx * 32 + j * 16 + m + dk) * 40 + q * 8];
          acc[0][j] = __builtin_amdgcn_mfma_f32_16x16x32_bf16(fa0, fb, acc[0][j], 0, 0, 0);
          acc[1][j] = __builtin_amdgcn_mfma_f32_16x16x32_bf16(fa1, fb, acc[1][j], 0, 0, 0);
        }
      }
      if (c0 < 7) {
        xstore(xa, xb, cur ? 0 : 2640);
        __syncthreads();
      }
      cur ^= 1;
    }
    #pragma unroll
    for (int i = 0; i < 2; ++i) {
      #pragma unroll
      for (int j = 0; j < 2; ++j) {
        #pragma unroll
        for (int r = 0; r < 4; ++r) {
          int co = co0 + wy * 32 + i * 16 + q * 4 + r;
          int t  = t0 + wx * 32 + j * 16 + m;
          if (t < 200) {
            float v = fmaxf(acc[i][j][r] + kb1[co], 0.f);
            kT1[((size_t)bb * 200 + t) * 512 + co] = f2bf(v);
          }
        }
      }
    }
  } else {
    // ---- QUERY CHAIN: xs2 @0 (dead after conv1), y1c @7680, y2c @0 ----
    const int qbid = blockIdx.x - 512;
    const int b = qbid / 13, t0 = (qbid % 13) * 64;
    short* xs2 = smem;            // [66][104] = 6864
    short* y1c = smem + 7680;     // [6][64][40] = 15360
    short* y2c = smem;            // [3][64][40] = 7680 (aliases xs2)

    floatx4 accq[3][4];
    #pragma unroll
    for (int f = 0; f < 3; ++f)
      #pragma unroll
      for (int tf = 0; tf < 4; ++tf) accq[f][tf] = (floatx4){0.f, 0.f, 0.f, 0.f};

    for (int i = tid; i < 66 * 12; i += 256) {
      int row = i / 12, g = i - (i / 12) * 12;
      int t = t0 + row - 1;
      int4 v = {0, 0, 0, 0};
      if (t >= 0 && t < 800)
        v = *(const int4*)&qT0[((size_t)b * 800 + t) * 96 + g * 8];
      *(int4*)&xs2[row * 104 + g * 8] = v;
    }
    __syncthreads();

    for (int c0 = 0; c0 < 3; ++c0) {
      #pragma unroll
      for (int dk = 0; dk < 3; ++dk) {
        short8 fa[3];
        #pragma unroll
        for (int f = 0; f < 3; ++f)
          fa[f] = *(const short8*)&w3[((size_t)(dk * 192 + wid * 48 + f * 16 + m)) * 96
                                      + c0 * 32 + q * 8];
        #pragma unroll
        for (int tf = 0; tf < 4; ++tf) {
          short8 fb = *(const short8*)&xs2[(tf * 16 + m + dk) * 104 + c0 * 32 + q * 8];
          #pragma unroll
          for (int f = 0; f < 3; ++f)
            accq[f][tf] = __builtin_amdgcn_mfma_f32_16x16x32_bf16(fa[f], fb, accq[f][tf], 0, 0, 0);
        }
      }
    }
    __syncthreads();
    #pragma unroll
    for (int f = 0; f < 3; ++f) {
      #pragma unroll
      for (int tf = 0; tf < 4; ++tf) {
        int co = wid * 48 + f * 16 + q * 4;
        int t  = tf * 16 + m;
        short4v o;
        #pragma unroll
        for (int r = 0; r < 4; ++r) {
          float bv = (co + r < 160) ? qb1[co + r] : 0.f;
          o[r] = f2bf(fmaxf(accq[f][tf][r] + bv, 0.f));
        }
        *(short4v*)&y1c[(co >> 5) * 2560 + t * 40 + (co & 31)] = o;
      }
    }
    __syncthreads();

    floatx4 acc2q[6];
    #pragma unroll
    for (int f = 0; f < 6; ++f) acc2q[f] = (floatx4){0.f, 0.f, 0.f, 0.f};
    #pragma unroll
    for (int c = 0; c < 6; ++c) {
      short8 fb = *(const short8*)&y1c[c * 2560 + (wid * 16 + m) * 40 + q * 8];
      #pragma unroll
      for (int f = 0; f < 6; ++f) {
        short8 fa = *(const short8*)&w4[((size_t)(f * 16 + m)) * 192 + c * 32 + q * 8];
        acc2q[f] = __builtin_amdgcn_mfma_f32_16x16x32_bf16(fa, fb, acc2q[f], 0, 0, 0);
      }
    }
    #pragma unroll
    for (int f = 0; f < 6; ++f) {
      int co = f * 16 + q * 4;
      int t  = wid * 16 + m;
      short4v o;
      #pragma unroll
      for (int r = 0; r < 4; ++r) {
        float bv = (co + r < 80) ? qb2[co + r] : 0.f;
        o[r] = f2bf(fmaxf(acc2q[f][r] + bv, 0.f));
      }
      *(short4v*)&y2c[(co >> 5) * 2560 + t * 40 + (co & 31)] = o;
    }
    __syncthreads();

    floatx4 acc3q[6];
    #pragma unroll
    for (int f = 0; f < 6; ++f) acc3q[f] = (floatx4){0.f, 0.f, 0.f, 0.f};
    #pragma unroll
    for (int c = 0; c < 3; ++c) {
      short8 fb = *(const short8*)&y2c[c * 2560 + (wid * 16 + m) * 40 + q * 8];
      #pragma unroll
      for (int f = 0; f < 6; ++f) {
        short8 fa = *(const short8*)&w5[((size_t)(f * 16 + m)) * 96 + c * 32 + q * 8];
        acc3q[f] = __builtin_amdgcn_mfma_f32_16x16x32_bf16(fa, fb, acc3q[f], 0, 0, 0);
      }
    }
    int t = t0 + wid * 16 + m;
    if (t < 800) {
      #pragma unroll
      for (int f = 0; f < 6; ++f) {
        int co = f * 16 + q * 4;
        short4v o;
        #pragma unroll
        for (int r = 0; r < 4; ++r) {
          float bv = (co + r < 80) ? qb3[co + r] : 0.f;
          o[r] = f2bf(acc3q[f][r] + bv);
        }
        *(short4v*)&qF[((size_t)b * 800 + t) * 96 + co] = o;
      }
    }
  }
}

// ===========================================================================
// kconv2 (r5-verified): key 512->80 k1, 208 one-wave blocks.
// ===========================================================================
__global__ __launch_bounds__(64) void kconv2_kernel(
    const short* __restrict__ kT1, const short* __restrict__ w2,
    const float* __restrict__ kb2, short* __restrict__ kF)
{
  const int blk = blockIdx.x;
  const int b = blk / 13, t0 = (blk - b * 13) * 16;
  const int lane = threadIdx.x & 63;
  const int q = lane >> 4, m = lane & 15;
  const int t = t0 + m;
  const bool tv = (t < 200);

  floatx4 acc[6];
  #pragma unroll
  for (int f = 0; f < 6; ++f) acc[f] = (floatx4){0.f, 0.f, 0.f, 0.f};

  #pragma unroll
  for (int c = 0; c < 16; ++c) {
    short8 fb;
    if (tv) fb = *(const short8*)&kT1[((size_t)b * 200 + t) * 512 + c * 32 + q * 8];
    else    fb = (short8){0,0,0,0,0,0,0,0};
    #pragma unroll
    for (int f = 0; f < 6; ++f) {
      short8 fa = *(const short8*)&w2[((size_t)(f * 16 + m)) * 512 + c * 32 + q * 8];
      acc[f] = __builtin_amdgcn_mfma_f32_16x16x32_bf16(fa, fb, acc[f], 0, 0, 0);
    }
  }
  if (tv) {
    #pragma unroll
    for (int f = 0; f < 6; ++f) {
      int co = f * 16 + q * 4;
      short4v o;
      #pragma unroll
      for (int r = 0; r < 4; ++r) {
        float bv = (co + r < 80) ? kb2[co + r] : 0.f;
        o[r] = f2bf(acc[f][r] + bv);
      }
      *(short4v*)&kF[((size_t)b * 200 + t) * 96 + co] = o;
    }
  }
}

// ===========================================================================
// Attention (r5-verified): S = q.k^T, q2 cancels, in-register log_softmax,
// LDS-staged coalesced float4 epilogue.
// ===========================================================================
__global__ __launch_bounds__(256) void attn_mfma(
    const short* __restrict__ qT, const short* __restrict__ kT,
    const float* __restrict__ prior, float* __restrict__ out)
{
  const int b = blockIdx.y, t1_0 = blockIdx.x * 64;
  const int tid = threadIdx.x, wid = tid >> 6, lane = tid & 63;
  const int q = lane >> 4, m = lane & 15;

  __shared__ __align__(16) char smem[51200];
  short* aq = (short*)smem;
  short* bk = (short*)(smem + 13312);
  float* k2s = (float*)(smem + 29952);
  float* sstage = (float*)smem;

  floatx4 acc[13];
  #pragma unroll
  for (int f = 0; f < 13; ++f) acc[f] = (floatx4){0.f, 0.f, 0.f, 0.f};

  for (int i = tid; i < 64 * 12; i += 256) {
    int row = i / 12, g = i - (i / 12) * 12;
    int4 v = {0, 0, 0, 0};
    if (t1_0 + row < 800)
      v = *(const int4*)&qT[((size_t)b * 800 + t1_0 + row) * 96 + g * 8];
    *(int4*)&aq[row * 104 + g * 8] = v;
  }

  float k2acc = 0.f;
  for (int c = 0; c < 3; ++c) {
    __syncthreads();
    for (int i = tid; i < 208 * 4; i += 256) {
      int row = i >> 2, g = i & 3;
      int4 v = {0, 0, 0, 0};
      if (row < 200)
        v = *(const int4*)&kT[((size_t)b * 200 + row) * 96 + c * 32 + g * 8];
      *(int4*)&bk[row * 40 + g * 8] = v;
    }
    __syncthreads();
    if (tid < 208) {
      #pragma unroll
      for (int g = 0; g < 4; ++g) {
        short8 s = *(const short8*)&bk[tid * 40 + g * 8];
        #pragma unroll
        for (int j = 0; j < 8; ++j) {
          union { unsigned u; float f; } x; x.u = ((unsigned)(unsigned short)s[j]) << 16;
          k2acc = fmaf(x.f, x.f, k2acc);
        }
      }
    }
    short8 fa = *(const short8*)&aq[(wid * 16 + m) * 104 + c * 32 + q * 8];
    #pragma unroll
    for (int f = 0; f < 13; ++f) {
      short8 fb = *(const short8*)&bk[(f * 16 + m) * 40 + q * 8];
      acc[f] = __builtin_amdgcn_mfma_f32_16x16x32_bf16(fa, fb, acc[f], 0, 0, 0);
    }
  }
  if (tid < 208) k2s[tid] = k2acc;
  __syncthreads();

  float k2v[13];
  #pragma unroll
  for (int f = 0; f < 13; ++f) k2v[f] = k2s[f * 16 + m];

  float mx[4] = {-INFINITY, -INFINITY, -INFINITY, -INFINITY};
  #pragma unroll
  for (int f = 0; f < 13; ++f) {
    bool valid = (f * 16 + m) < 200;
    #pragma unroll
    for (int r = 0; r < 4; ++r) {
      float v = valid ? (0.001f * acc[f][r] - 0.0005f * k2v[f]) : -INFINITY;
      acc[f][r] = v;
      mx[r] = fmaxf(mx[r], v);
    }
  }
  #pragma unroll
  for (int msk = 1; msk < 16; msk <<= 1)
    #pragma unroll
    for (int r = 0; r < 4; ++r) mx[r] = fmaxf(mx[r], __shfl_xor(mx[r], msk));
  float sm[4] = {0.f, 0.f, 0.f, 0.f};
  #pragma unroll
  for (int f = 0; f < 13; ++f)
    #pragma unroll
    for (int r = 0; r < 4; ++r) sm[r] += __expf(acc[f][r] - mx[r]);
  #pragma unroll
  for (int msk = 1; msk < 16; msk <<= 1)
    #pragma unroll
    for (int r = 0; r < 4; ++r) sm[r] += __shfl_xor(sm[r], msk);
  float lse[4];
  #pragma unroll
  for (int r = 0; r < 4; ++r) lse[r] = mx[r] + __logf(sm[r]);

  __syncthreads();
  #pragma unroll
  for (int f = 0; f < 13; ++f) {
    int col = f * 16 + m;
    if (col < 200) {
      #pragma unroll
      for (int r = 0; r < 4; ++r)
        sstage[(wid * 16 + q * 4 + r) * 200 + col] = acc[f][r] - lse[r];
    }
  }
  __syncthreads();

  for (int i = tid; i < 64 * 50; i += 256) {
    int row = i / 50, seg = i - (i / 50) * 50;
    int t1 = t1_0 + row;
    if (t1 < 800) {
      size_t o = ((size_t)b * 800 + t1) * 200 + seg * 4;
      floatx4 pv = *(const floatx4*)&prior[o];
      floatx4 sv = *(const floatx4*)&sstage[row * 200 + seg * 4];
      floatx4 ov;
      #pragma unroll
      for (int j = 0; j < 4; ++j) ov[j] = sv[j] + __logf(pv[j] + 1e-8f);
      *(floatx4*)&out[o] = ov;
    }
  }
}

extern "C" void kernel_launch(void* const* d_in, const int* in_sizes, int n_in,
                              void* d_out, int out_size, void* d_ws, size_t ws_size,
                              hipStream_t stream) {
  const float* queries = (const float*)d_in[0];
  const float* keys    = (const float*)d_in[1];
  const float* prior   = (const float*)d_in[2];
  const float* kw1 = (const float*)d_in[3];
  const float* kb1 = (const float*)d_in[4];
  const float* kw2 = (const float*)d_in[5];
  const float* kb2 = (const float*)d_in[6];
  const float* qw1 = (const float*)d_in[7];
  const float* qb1 = (const float*)d_in[8];
  const float* qw2 = (const float*)d_in[9];
  const float* qb2 = (const float*)d_in[10];
  const float* qw3 = (const float*)d_in[11];
  const float* qb3 = (const float*)d_in[12];
  float* out = (float*)d_out;

  short* p = (short*)d_ws;
  short* kT0 = p;  p += (size_t)3200 * 256;
  short* qT0 = p;  p += (size_t)12800 * 96;
  short* w1  = p;  p += (size_t)3 * 512 * 256;
  short* w2  = p;  p += (size_t)96 * 512;
  short* w3  = p;  p += (size_t)3 * 192 * 96;
  short* w4  = p;  p += (size_t)96 * 192;
  short* w5  = p;  p += (size_t)96 * 96;
  short* kT1 = p;  p += (size_t)3200 * 512;
  short* kF  = p;  p += (size_t)3200 * 96;
  short* qF  = p;  p += (size_t)12800 * 96;

  prep_kernel<<<dim3(1649), 256, 0, stream>>>(keys, queries, kw1, kw2, qw1, qw2, qw3,
                                              kT0, qT0, w1, w2, w3, w4, w5);
  conv_k3_kernel<<<dim3(720), 256, 0, stream>>>(kT0, qT0, w1, w3, w4, w5,
                                                kb1, qb1, qb2, qb3, kT1, qF);
  kconv2_kernel<<<dim3(208), 64, 0, stream>>>(kT1, w2, kb2, kF);
  attn_mfma<<<dim3(13, 16), 256, 0, stream>>>(qF, kF, prior, out);
}